// Round 1
// baseline (267.875 us; speedup 1.0000x reference)
//
#include <hip/hip_runtime.h>
#include <math.h>

#define NN 8
#define CC 256
#define HH 112
#define WW 112
#define MIP 8
#define EPS 1e-5f

// ---------------------------------------------------------------------------
// Kernel 1: dual-axis average pooling.
// One block per (n,c) plane (2048 blocks). Plane = 112x112 fp32 = 50 KB.
// Phase A: column means (mean over H) -> w-branch, coalesced across lanes.
// Phase B: row means (mean over W) -> h-branch, re-read from L1/L2 (plane hot).
// pool layout: [branch0: N*C*H floats][branch1: N*C*W floats]
// ---------------------------------------------------------------------------
__global__ __launch_bounds__(128) void pool_kernel(const float* __restrict__ x,
                                                   float* __restrict__ pool) {
    const int b = blockIdx.x;            // n*C + c
    const int tid = threadIdx.x;
    const float* plane = x + (size_t)b * (HH * WW);

    // column sums: mean over h -> x_w  (branch 1)
    if (tid < WW) {
        float s = 0.f;
#pragma unroll 4
        for (int h = 0; h < HH; ++h) s += plane[h * WW + tid];
        pool[(size_t)(NN * CC * HH) + (size_t)b * WW + tid] = s * (1.0f / HH);
    }
    // row sums: mean over w -> x_h  (branch 0)
    if (tid < HH) {
        float s = 0.f;
#pragma unroll 4
        for (int w = 0; w < WW; ++w) s += plane[tid * WW + w];
        pool[(size_t)b * HH + tid] = s * (1.0f / WW);
    }
}

// ---------------------------------------------------------------------------
// Kernel 2: BN -> conv1x1(C->MIP) -> relu -> conv1x1(MIP->C) -> sigmoid.
// grid = (N*112, 2): blockIdx.y = branch (0:h uses bn1, 1:w uses bn2),
// blockIdx.x = n*112 + pos. 256 threads = one channel each.
// Attention written IN PLACE over the pooled buffer (same coords, barrier-
// separated within the block; no cross-block aliasing).
// ---------------------------------------------------------------------------
__global__ __launch_bounds__(256) void att_kernel(
    float* __restrict__ pool,
    const float* __restrict__ bn1_g, const float* __restrict__ bn1_b,
    const float* __restrict__ bn1_m, const float* __restrict__ bn1_v,
    const float* __restrict__ bn2_g, const float* __restrict__ bn2_b,
    const float* __restrict__ bn2_m, const float* __restrict__ bn2_v,
    const float* __restrict__ ds_w, const float* __restrict__ ds_b,
    const float* __restrict__ us_w, const float* __restrict__ us_b) {
    __shared__ float s[CC];
    __shared__ float dsh[MIP];

    const int n = blockIdx.x / HH;
    const int pos = blockIdx.x % HH;
    const int branch = blockIdx.y;
    const int c = threadIdx.x;

    const float* g  = branch ? bn2_g : bn1_g;
    const float* be = branch ? bn2_b : bn1_b;
    const float* mn = branch ? bn2_m : bn1_m;
    const float* vr = branch ? bn2_v : bn1_v;

    const size_t base = (size_t)branch * (NN * CC * HH);
    const size_t idx = base + ((size_t)(n * CC + c)) * HH + pos;

    float v = pool[idx];
    float scale = g[c] * rsqrtf(vr[c] + EPS);
    float vb = v * scale + (be[c] - mn[c] * scale);
    s[c] = vb;
    __syncthreads();

    // C->MIP reduce: 8 groups of 32 lanes, strided partials + shuffle tree
    {
        const int grp = c >> 5;      // 0..7 = mip index
        const int l = c & 31;
        float partial = 0.f;
#pragma unroll
        for (int k = 0; k < CC / 32; ++k) {
            const int cc = l + k * 32;
            partial += ds_w[grp * CC + cc] * s[cc];
        }
#pragma unroll
        for (int off = 16; off > 0; off >>= 1)
            partial += __shfl_down(partial, off, 32);
        if (l == 0) dsh[grp] = fmaxf(partial + ds_b[grp], 0.f);
    }
    __syncthreads();

    // MIP->C expand + sigmoid
    float acc = us_b[c];
#pragma unroll
    for (int m = 0; m < MIP; ++m) acc += us_w[c * MIP + m] * dsh[m];
    float a = 1.0f / (1.0f + expf(-acc));
    pool[idx] = a;
}

// ---------------------------------------------------------------------------
// Kernel 3: elementwise apply + h-swish, float4-vectorized.
// out = o * clamp(o+3,0,6)/6  where  o = x*aw*ah + x
// ---------------------------------------------------------------------------
__global__ __launch_bounds__(256) void apply_kernel(const float* __restrict__ x,
                                                    const float* __restrict__ att,
                                                    float* __restrict__ out) {
    const int idx = blockIdx.x * 256 + threadIdx.x;   // float4 index
    const int W4 = WW / 4;                            // 28
    const int w4 = idx % W4;
    const int r = idx / W4;
    const int h = r % HH;
    const int nc = r / HH;                            // n*C + c

    float4 xv = ((const float4*)x)[idx];
    float ah = att[(size_t)nc * HH + h];
    float4 aw = ((const float4*)(att + (size_t)NN * CC * HH))[(size_t)nc * W4 + w4];

    float4 o;
    o.x = xv.x * (aw.x * ah) + xv.x;
    o.y = xv.y * (aw.y * ah) + xv.y;
    o.z = xv.z * (aw.z * ah) + xv.z;
    o.w = xv.w * (aw.w * ah) + xv.w;

    float4 res;
    res.x = o.x * fminf(fmaxf(o.x + 3.0f, 0.0f), 6.0f) * (1.0f / 6.0f);
    res.y = o.y * fminf(fmaxf(o.y + 3.0f, 0.0f), 6.0f) * (1.0f / 6.0f);
    res.z = o.z * fminf(fmaxf(o.z + 3.0f, 0.0f), 6.0f) * (1.0f / 6.0f);
    res.w = o.w * fminf(fmaxf(o.w + 3.0f, 0.0f), 6.0f) * (1.0f / 6.0f);

    ((float4*)out)[idx] = res;
}

extern "C" void kernel_launch(void* const* d_in, const int* in_sizes, int n_in,
                              void* d_out, int out_size, void* d_ws, size_t ws_size,
                              hipStream_t stream) {
    const float* x     = (const float*)d_in[0];
    const float* bn1_g = (const float*)d_in[1];
    const float* bn1_b = (const float*)d_in[2];
    const float* bn1_m = (const float*)d_in[3];
    const float* bn1_v = (const float*)d_in[4];
    const float* bn2_g = (const float*)d_in[5];
    const float* bn2_b = (const float*)d_in[6];
    const float* bn2_m = (const float*)d_in[7];
    const float* bn2_v = (const float*)d_in[8];
    const float* ds_w  = (const float*)d_in[9];
    const float* ds_b  = (const float*)d_in[10];
    const float* us_w  = (const float*)d_in[11];
    const float* us_b  = (const float*)d_in[12];
    float* out = (float*)d_out;
    float* pool = (float*)d_ws;   // needs 2*N*C*112*4 = 1.75 MB

    pool_kernel<<<NN * CC, 128, 0, stream>>>(x, pool);
    att_kernel<<<dim3(NN * HH, 2), 256, 0, stream>>>(pool,
        bn1_g, bn1_b, bn1_m, bn1_v, bn2_g, bn2_b, bn2_m, bn2_v,
        ds_w, ds_b, us_w, us_b);
    const int total4 = NN * CC * HH * WW / 4;
    apply_kernel<<<total4 / 256, 256, 0, stream>>>(x, pool, out);
}

// Round 2
// 224.961 us; speedup vs baseline: 1.1908x; 1.1908x over previous
//
#include <hip/hip_runtime.h>
#include <math.h>

#define NN 8
#define CC 256
#define HH 112
#define WW 112
#define MIP 8
#define EPS 1e-5f

// Pooled/attention buffer layout (position-major, channel-contiguous):
//   branch 0 (h-pool): P[((n*HH + h)*CC + c)]
//   branch 1 (w-pool): P[NN*HH*CC + ((n*WW + w)*CC + c)]
// This makes att_kernel fully coalesced; pool (writes) and apply (reads)
// eat small per-block scatters into an L2-resident 1.75 MB buffer.

// ---------------------------------------------------------------------------
// Kernel 1: dual-axis average pooling, SINGLE pass over x.
// One block per (n,c) plane. Stage plane in LDS (row stride 113 -> both
// row-direction and column-direction b32 reads are bank-conflict-free),
// then waves 0-1 do row means while waves 2-3 do column means.
// ---------------------------------------------------------------------------
#define TSTRIDE 113
__global__ __launch_bounds__(256) void pool_kernel(const float* __restrict__ x,
                                                   float* __restrict__ pool) {
    __shared__ float tile[HH * TSTRIDE];   // 50.6 KB -> 3 blocks/CU
    const int b = blockIdx.x;              // n*CC + c
    const int n = b / CC;
    const int c = b % CC;
    const int tid = threadIdx.x;

    const float4* p4 = (const float4*)(x + (size_t)b * (HH * WW));
#pragma unroll 4
    for (int i = tid; i < HH * (WW / 4); i += 256) {
        float4 v = p4[i];
        const int h = i / (WW / 4);
        const int w4 = i % (WW / 4);
        float* d = &tile[h * TSTRIDE + w4 * 4];
        d[0] = v.x; d[1] = v.y; d[2] = v.z; d[3] = v.w;
    }
    __syncthreads();

    if (tid < HH) {
        // row mean (mean over w) -> h-branch
        float s = 0.f;
#pragma unroll 8
        for (int w = 0; w < WW; ++w) s += tile[tid * TSTRIDE + w];
        pool[((size_t)(n * HH + tid)) * CC + c] = s * (1.0f / WW);
    } else if (tid >= 128 && tid < 128 + WW) {
        // column mean (mean over h) -> w-branch
        const int w = tid - 128;
        float s = 0.f;
#pragma unroll 8
        for (int h = 0; h < HH; ++h) s += tile[h * TSTRIDE + w];
        pool[(size_t)(NN * HH * CC) + ((size_t)(n * WW + w)) * CC + c] = s * (1.0f / HH);
    }
}

// ---------------------------------------------------------------------------
// Kernel 2: BN -> conv1x1(C->MIP) -> relu -> conv1x1(MIP->C) -> sigmoid.
// grid = (N*112, 2). 256 threads = one channel each. All pool accesses are
// now channel-contiguous -> fully coalesced. In-place update (block-private
// coords, barrier-separated).
// ---------------------------------------------------------------------------
__global__ __launch_bounds__(256) void att_kernel(
    float* __restrict__ pool,
    const float* __restrict__ bn1_g, const float* __restrict__ bn1_b,
    const float* __restrict__ bn1_m, const float* __restrict__ bn1_v,
    const float* __restrict__ bn2_g, const float* __restrict__ bn2_b,
    const float* __restrict__ bn2_m, const float* __restrict__ bn2_v,
    const float* __restrict__ ds_w, const float* __restrict__ ds_b,
    const float* __restrict__ us_w, const float* __restrict__ us_b) {
    __shared__ float s[CC];
    __shared__ float dsh[MIP];

    const int branch = blockIdx.y;
    const int c = threadIdx.x;

    const float* g  = branch ? bn2_g : bn1_g;
    const float* be = branch ? bn2_b : bn1_b;
    const float* mn = branch ? bn2_m : bn1_m;
    const float* vr = branch ? bn2_v : bn1_v;

    const size_t idx = (size_t)branch * (NN * HH * CC) + (size_t)blockIdx.x * CC + c;

    float v = pool[idx];
    float scale = g[c] * rsqrtf(vr[c] + EPS);
    float vb = v * scale + (be[c] - mn[c] * scale);
    s[c] = vb;
    __syncthreads();

    // C->MIP reduce: 8 groups of 32 lanes
    {
        const int grp = c >> 5;
        const int l = c & 31;
        float partial = 0.f;
#pragma unroll
        for (int k = 0; k < CC / 32; ++k) {
            const int cc = l + k * 32;
            partial += ds_w[grp * CC + cc] * s[cc];
        }
#pragma unroll
        for (int off = 16; off > 0; off >>= 1)
            partial += __shfl_down(partial, off, 32);
        if (l == 0) dsh[grp] = fmaxf(partial + ds_b[grp], 0.f);
    }
    __syncthreads();

    float acc = us_b[c];
#pragma unroll
    for (int m = 0; m < MIP; ++m) acc += us_w[c * MIP + m] * dsh[m];
    pool[idx] = 1.0f / (1.0f + expf(-acc));
}

// ---------------------------------------------------------------------------
// Kernel 3: apply + h-swish. One block per (n,c) plane: stage this plane's
// 112 ah + 112 aw attention scalars into LDS once, then stream x -> out
// fully float4-coalesced with LDS-only attention lookups.
// ---------------------------------------------------------------------------
__global__ __launch_bounds__(256) void apply_kernel(const float* __restrict__ x,
                                                    const float* __restrict__ att,
                                                    float* __restrict__ out) {
    __shared__ float ah[HH];
    __shared__ float aw[WW];
    const int b = blockIdx.x;              // n*CC + c
    const int n = b / CC;
    const int c = b % CC;
    const int tid = threadIdx.x;

    if (tid < HH) {
        ah[tid] = att[((size_t)(n * HH + tid)) * CC + c];
    } else if (tid >= 128 && tid < 128 + WW) {
        const int w = tid - 128;
        aw[w] = att[(size_t)(NN * HH * CC) + ((size_t)(n * WW + w)) * CC + c];
    }
    __syncthreads();

    const float4* xp = (const float4*)(x + (size_t)b * (HH * WW));
    float4* op = (float4*)(out + (size_t)b * (HH * WW));
#pragma unroll 4
    for (int i = tid; i < HH * (WW / 4); i += 256) {
        const int h = i / (WW / 4);
        const int w4 = i % (WW / 4);
        float4 xv = xp[i];
        const float a_h = ah[h];
        float4 o;
        o.x = xv.x * (aw[w4 * 4 + 0] * a_h) + xv.x;
        o.y = xv.y * (aw[w4 * 4 + 1] * a_h) + xv.y;
        o.z = xv.z * (aw[w4 * 4 + 2] * a_h) + xv.z;
        o.w = xv.w * (aw[w4 * 4 + 3] * a_h) + xv.w;
        float4 r;
        r.x = o.x * fminf(fmaxf(o.x + 3.0f, 0.0f), 6.0f) * (1.0f / 6.0f);
        r.y = o.y * fminf(fmaxf(o.y + 3.0f, 0.0f), 6.0f) * (1.0f / 6.0f);
        r.z = o.z * fminf(fmaxf(o.z + 3.0f, 0.0f), 6.0f) * (1.0f / 6.0f);
        r.w = o.w * fminf(fmaxf(o.w + 3.0f, 0.0f), 6.0f) * (1.0f / 6.0f);
        op[i] = r;
    }
}

extern "C" void kernel_launch(void* const* d_in, const int* in_sizes, int n_in,
                              void* d_out, int out_size, void* d_ws, size_t ws_size,
                              hipStream_t stream) {
    const float* x     = (const float*)d_in[0];
    const float* bn1_g = (const float*)d_in[1];
    const float* bn1_b = (const float*)d_in[2];
    const float* bn1_m = (const float*)d_in[3];
    const float* bn1_v = (const float*)d_in[4];
    const float* bn2_g = (const float*)d_in[5];
    const float* bn2_b = (const float*)d_in[6];
    const float* bn2_m = (const float*)d_in[7];
    const float* bn2_v = (const float*)d_in[8];
    const float* ds_w  = (const float*)d_in[9];
    const float* ds_b  = (const float*)d_in[10];
    const float* us_w  = (const float*)d_in[11];
    const float* us_b  = (const float*)d_in[12];
    float* out = (float*)d_out;
    float* pool = (float*)d_ws;   // 2*N*112*C*4 = 1.75 MB

    pool_kernel<<<NN * CC, 256, 0, stream>>>(x, pool);
    att_kernel<<<dim3(NN * HH, 2), 256, 0, stream>>>(pool,
        bn1_g, bn1_b, bn1_m, bn1_v, bn2_g, bn2_b, bn2_m, bn2_v,
        ds_w, ds_b, us_w, us_b);
    apply_kernel<<<NN * CC, 256, 0, stream>>>(x, pool, out);
}

// Round 4
// 224.754 us; speedup vs baseline: 1.1919x; 1.0009x over previous
//
#include <hip/hip_runtime.h>
#include <math.h>

#define NN 8
#define CC 256
#define HH 112
#define WW 112
#define MIP 8
#define EPS 1e-5f

typedef float nvec4 __attribute__((ext_vector_type(4)));   // native vec for nontemporal builtins

// Pooled/attention buffer layout (position-major, channel-contiguous):
//   branch 0 (h-pool): P[((n*HH + h)*CC + c)]
//   branch 1 (w-pool): P[NN*HH*CC + ((n*WW + w)*CC + c)]

// ---------------------------------------------------------------------------
// Kernel 1: dual-axis average pooling, single pass, register accumulators.
// One block (256 thr) per (n,c) plane. Threads t<224: (g=t/28, j=t%28),
// thread reads rows g+8k (k=0..13) at float4 column j. 14 independent global
// loads per thread, no LDS in the loop -> full 8 blocks/CU occupancy.
// ---------------------------------------------------------------------------
__global__ __launch_bounds__(256) void pool_kernel(const float* __restrict__ x,
                                                   float* __restrict__ pool) {
    __shared__ float rowpart[HH][29];        // 12.7 KB
    __shared__ float4 colpart[8][28];        // 3.5 KB
    const int b = blockIdx.x;                // n*CC + c
    const int n = b / CC;
    const int c = b % CC;
    const int t = threadIdx.x;

    const float4* p4 = (const float4*)(x + (size_t)b * (HH * WW));

    if (t < 224) {
        const int g = t / 28;                // row group 0..7
        const int j = t % 28;                // float4 column 0..27
        float4 ca = make_float4(0.f, 0.f, 0.f, 0.f);
#pragma unroll
        for (int k = 0; k < 14; ++k) {
            const int r = g + 8 * k;
            float4 v = p4[r * 28 + j];
            ca.x += v.x; ca.y += v.y; ca.z += v.z; ca.w += v.w;
            rowpart[r][j] = v.x + v.y + v.z + v.w;
        }
        colpart[g][j] = ca;
    }
    __syncthreads();

    if (t < HH) {
        // row mean (over w) -> h-branch
        float s = 0.f;
#pragma unroll
        for (int j = 0; j < 28; ++j) s += rowpart[t][j];
        pool[((size_t)(n * HH + t)) * CC + c] = s * (1.0f / WW);
    } else if (t < 112 + WW) {
        // column mean (over h) -> w-branch
        const int w = t - 112;
        const float* cp = (const float*)&colpart[0][0];   // [8][112] floats
        float s = 0.f;
#pragma unroll
        for (int g = 0; g < 8; ++g) s += cp[g * 112 + w];
        pool[(size_t)(NN * HH * CC) + ((size_t)(n * WW + w)) * CC + c] = s * (1.0f / HH);
    }
}

// ---------------------------------------------------------------------------
// Kernel 2: BN -> conv1x1(C->MIP) -> relu -> conv1x1(MIP->C) -> sigmoid.
// grid = (N*112, 2). 256 threads = one channel each, fully coalesced.
// In-place update of the pooled buffer (block-private coords).
// ---------------------------------------------------------------------------
__global__ __launch_bounds__(256) void att_kernel(
    float* __restrict__ pool,
    const float* __restrict__ bn1_g, const float* __restrict__ bn1_b,
    const float* __restrict__ bn1_m, const float* __restrict__ bn1_v,
    const float* __restrict__ bn2_g, const float* __restrict__ bn2_b,
    const float* __restrict__ bn2_m, const float* __restrict__ bn2_v,
    const float* __restrict__ ds_w, const float* __restrict__ ds_b,
    const float* __restrict__ us_w, const float* __restrict__ us_b) {
    __shared__ float s[CC];
    __shared__ float dsh[MIP];

    const int branch = blockIdx.y;
    const int c = threadIdx.x;

    const float* g  = branch ? bn2_g : bn1_g;
    const float* be = branch ? bn2_b : bn1_b;
    const float* mn = branch ? bn2_m : bn1_m;
    const float* vr = branch ? bn2_v : bn1_v;

    const size_t idx = (size_t)branch * (NN * HH * CC) + (size_t)blockIdx.x * CC + c;

    float v = pool[idx];
    float scale = g[c] * rsqrtf(vr[c] + EPS);
    float vb = v * scale + (be[c] - mn[c] * scale);
    s[c] = vb;
    __syncthreads();

    {
        const int grp = c >> 5;
        const int l = c & 31;
        float partial = 0.f;
#pragma unroll
        for (int k = 0; k < CC / 32; ++k) {
            const int cc = l + k * 32;
            partial += ds_w[grp * CC + cc] * s[cc];
        }
#pragma unroll
        for (int off = 16; off > 0; off >>= 1)
            partial += __shfl_down(partial, off, 32);
        if (l == 0) dsh[grp] = fmaxf(partial + ds_b[grp], 0.f);
    }
    __syncthreads();

    float acc = us_b[c];
#pragma unroll
    for (int m = 0; m < MIP; ++m) acc += us_w[c * MIP + m] * dsh[m];
    pool[idx] = 1.0f / (1.0f + expf(-acc));
}

// ---------------------------------------------------------------------------
// Kernel 3: apply + h-swish. One block per (n,c) plane: stage 112 ah + 112 aw
// into LDS, then stream x -> out float4-coalesced with non-temporal
// loads/stores on the big streams.
// ---------------------------------------------------------------------------
__global__ __launch_bounds__(256) void apply_kernel(const float* __restrict__ x,
                                                    const float* __restrict__ att,
                                                    float* __restrict__ out) {
    __shared__ float ah[HH];
    __shared__ float aw[WW];
    const int b = blockIdx.x;              // n*CC + c
    const int n = b / CC;
    const int c = b % CC;
    const int tid = threadIdx.x;

    if (tid < HH) {
        ah[tid] = att[((size_t)(n * HH + tid)) * CC + c];
    } else if (tid >= 128 && tid < 128 + WW) {
        const int w = tid - 128;
        aw[w] = att[(size_t)(NN * HH * CC) + ((size_t)(n * WW + w)) * CC + c];
    }
    __syncthreads();

    const nvec4* xp = (const nvec4*)(x + (size_t)b * (HH * WW));
    nvec4* op = (nvec4*)(out + (size_t)b * (HH * WW));
#pragma unroll 4
    for (int i = tid; i < HH * (WW / 4); i += 256) {
        const int h = i / (WW / 4);
        const int w4 = i % (WW / 4);
        nvec4 xv = __builtin_nontemporal_load(&xp[i]);
        const float a_h = ah[h];
        nvec4 o;
        o.x = xv.x * (aw[w4 * 4 + 0] * a_h) + xv.x;
        o.y = xv.y * (aw[w4 * 4 + 1] * a_h) + xv.y;
        o.z = xv.z * (aw[w4 * 4 + 2] * a_h) + xv.z;
        o.w = xv.w * (aw[w4 * 4 + 3] * a_h) + xv.w;
        nvec4 r;
        r.x = o.x * fminf(fmaxf(o.x + 3.0f, 0.0f), 6.0f) * (1.0f / 6.0f);
        r.y = o.y * fminf(fmaxf(o.y + 3.0f, 0.0f), 6.0f) * (1.0f / 6.0f);
        r.z = o.z * fminf(fmaxf(o.z + 3.0f, 0.0f), 6.0f) * (1.0f / 6.0f);
        r.w = o.w * fminf(fmaxf(o.w + 3.0f, 0.0f), 6.0f) * (1.0f / 6.0f);
        __builtin_nontemporal_store(r, &op[i]);
    }
}

extern "C" void kernel_launch(void* const* d_in, const int* in_sizes, int n_in,
                              void* d_out, int out_size, void* d_ws, size_t ws_size,
                              hipStream_t stream) {
    const float* x     = (const float*)d_in[0];
    const float* bn1_g = (const float*)d_in[1];
    const float* bn1_b = (const float*)d_in[2];
    const float* bn1_m = (const float*)d_in[3];
    const float* bn1_v = (const float*)d_in[4];
    const float* bn2_g = (const float*)d_in[5];
    const float* bn2_b = (const float*)d_in[6];
    const float* bn2_m = (const float*)d_in[7];
    const float* bn2_v = (const float*)d_in[8];
    const float* ds_w  = (const float*)d_in[9];
    const float* ds_b  = (const float*)d_in[10];
    const float* us_w  = (const float*)d_in[11];
    const float* us_b  = (const float*)d_in[12];
    float* out = (float*)d_out;
    float* pool = (float*)d_ws;   // 2*N*112*C*4 = 1.75 MB

    pool_kernel<<<NN * CC, 256, 0, stream>>>(x, pool);
    att_kernel<<<dim3(NN * HH, 2), 256, 0, stream>>>(pool,
        bn1_g, bn1_b, bn1_m, bn1_v, bn2_g, bn2_b, bn2_m, bn2_v,
        ds_w, ds_b, us_w, us_b);
    apply_kernel<<<NN * CC, 256, 0, stream>>>(x, pool, out);
}

// Round 6
// 223.112 us; speedup vs baseline: 1.2006x; 1.0074x over previous
//
#include <hip/hip_runtime.h>
#include <math.h>

#define NN 8
#define CC 256
#define HH 112
#define WW 112
#define MIP 8
#define EPS 1e-5f

typedef float nvec4 __attribute__((ext_vector_type(4)));   // native vec for nontemporal builtins

// Pooled/attention buffer layout (position-major, channel-contiguous):
//   branch 0 (h-pool): P[((n*HH + h)*CC + c)]
//   branch 1 (w-pool): P[NN*HH*CC + ((n*WW + w)*CC + c)]

// ---------------------------------------------------------------------------
// Kernel 1: dual-axis average pooling, single pass, register accumulators.
// One block (256 thr) per (n,c) plane. Threads t<224: (g=t/28, j=t%28),
// thread reads rows g+8k (k=0..13) at float4 column j via NON-TEMPORAL loads
// (x is read-once here; avoid allocating into a poison-dirty L3 -> no forced
// eviction writebacks competing with the read stream).
// ---------------------------------------------------------------------------
__global__ __launch_bounds__(256) void pool_kernel(const float* __restrict__ x,
                                                   float* __restrict__ pool) {
    __shared__ float rowpart[HH][29];        // 12.7 KB
    __shared__ float4 colpart[8][28];        // 3.5 KB
    const int b = blockIdx.x;                // n*CC + c
    const int n = b / CC;
    const int c = b % CC;
    const int t = threadIdx.x;

    const nvec4* p4 = (const nvec4*)(x + (size_t)b * (HH * WW));

    if (t < 224) {
        const int g = t / 28;                // row group 0..7
        const int j = t % 28;                // float4 column 0..27
        float4 ca = make_float4(0.f, 0.f, 0.f, 0.f);
#pragma unroll
        for (int k = 0; k < 14; ++k) {
            const int r = g + 8 * k;
            nvec4 v = __builtin_nontemporal_load(&p4[r * 28 + j]);
            ca.x += v.x; ca.y += v.y; ca.z += v.z; ca.w += v.w;
            rowpart[r][j] = v.x + v.y + v.z + v.w;
        }
        colpart[g][j] = ca;
    }
    __syncthreads();

    if (t < HH) {
        // row mean (over w) -> h-branch
        float s = 0.f;
#pragma unroll
        for (int j = 0; j < 28; ++j) s += rowpart[t][j];
        pool[((size_t)(n * HH + t)) * CC + c] = s * (1.0f / WW);
    } else if (t < 112 + WW) {
        // column mean (over h) -> w-branch
        const int w = t - 112;
        const float* cp = (const float*)&colpart[0][0];   // [8][112] floats
        float s = 0.f;
#pragma unroll
        for (int g = 0; g < 8; ++g) s += cp[g * 112 + w];
        pool[(size_t)(NN * HH * CC) + ((size_t)(n * WW + w)) * CC + c] = s * (1.0f / HH);
    }
}

// ---------------------------------------------------------------------------
// Kernel 2: BN -> conv1x1(C->MIP) -> relu -> conv1x1(MIP->C) -> sigmoid.
// grid = (N*112, 2). 256 threads = one channel each, fully coalesced.
// In-place update of the pooled buffer (block-private coords).
// ---------------------------------------------------------------------------
__global__ __launch_bounds__(256) void att_kernel(
    float* __restrict__ pool,
    const float* __restrict__ bn1_g, const float* __restrict__ bn1_b,
    const float* __restrict__ bn1_m, const float* __restrict__ bn1_v,
    const float* __restrict__ bn2_g, const float* __restrict__ bn2_b,
    const float* __restrict__ bn2_m, const float* __restrict__ bn2_v,
    const float* __restrict__ ds_w, const float* __restrict__ ds_b,
    const float* __restrict__ us_w, const float* __restrict__ us_b) {
    __shared__ float s[CC];
    __shared__ float dsh[MIP];

    const int branch = blockIdx.y;
    const int c = threadIdx.x;

    const float* g  = branch ? bn2_g : bn1_g;
    const float* be = branch ? bn2_b : bn1_b;
    const float* mn = branch ? bn2_m : bn1_m;
    const float* vr = branch ? bn2_v : bn1_v;

    const size_t idx = (size_t)branch * (NN * HH * CC) + (size_t)blockIdx.x * CC + c;

    float v = pool[idx];
    float scale = g[c] * rsqrtf(vr[c] + EPS);
    float vb = v * scale + (be[c] - mn[c] * scale);
    s[c] = vb;
    __syncthreads();

    {
        const int grp = c >> 5;
        const int l = c & 31;
        float partial = 0.f;
#pragma unroll
        for (int k = 0; k < CC / 32; ++k) {
            const int cc = l + k * 32;
            partial += ds_w[grp * CC + cc] * s[cc];
        }
#pragma unroll
        for (int off = 16; off > 0; off >>= 1)
            partial += __shfl_down(partial, off, 32);
        if (l == 0) dsh[grp] = fmaxf(partial + ds_b[grp], 0.f);
    }
    __syncthreads();

    float acc = us_b[c];
#pragma unroll
    for (int m = 0; m < MIP; ++m) acc += us_w[c * MIP + m] * dsh[m];
    pool[idx] = 1.0f / (1.0f + expf(-acc));
}

// ---------------------------------------------------------------------------
// Kernel 3: apply + h-swish. One block per (n,c) plane: stage 112 ah + 112 aw
// into LDS, then stream x -> out float4-coalesced with non-temporal
// loads/stores on the big streams.
// ---------------------------------------------------------------------------
__global__ __launch_bounds__(256) void apply_kernel(const float* __restrict__ x,
                                                    const float* __restrict__ att,
                                                    float* __restrict__ out) {
    __shared__ float ah[HH];
    __shared__ float aw[WW];
    const int b = blockIdx.x;              // n*CC + c
    const int n = b / CC;
    const int c = b % CC;
    const int tid = threadIdx.x;

    if (tid < HH) {
        ah[tid] = att[((size_t)(n * HH + tid)) * CC + c];
    } else if (tid >= 128 && tid < 128 + WW) {
        const int w = tid - 128;
        aw[w] = att[(size_t)(NN * HH * CC) + ((size_t)(n * WW + w)) * CC + c];
    }
    __syncthreads();

    const nvec4* xp = (const nvec4*)(x + (size_t)b * (HH * WW));
    nvec4* op = (nvec4*)(out + (size_t)b * (HH * WW));
#pragma unroll 4
    for (int i = tid; i < HH * (WW / 4); i += 256) {
        const int h = i / (WW / 4);
        const int w4 = i % (WW / 4);
        nvec4 xv = __builtin_nontemporal_load(&xp[i]);
        const float a_h = ah[h];
        nvec4 o;
        o.x = xv.x * (aw[w4 * 4 + 0] * a_h) + xv.x;
        o.y = xv.y * (aw[w4 * 4 + 1] * a_h) + xv.y;
        o.z = xv.z * (aw[w4 * 4 + 2] * a_h) + xv.z;
        o.w = xv.w * (aw[w4 * 4 + 3] * a_h) + xv.w;
        nvec4 r;
        r.x = o.x * fminf(fmaxf(o.x + 3.0f, 0.0f), 6.0f) * (1.0f / 6.0f);
        r.y = o.y * fminf(fmaxf(o.y + 3.0f, 0.0f), 6.0f) * (1.0f / 6.0f);
        r.z = o.z * fminf(fmaxf(o.z + 3.0f, 0.0f), 6.0f) * (1.0f / 6.0f);
        r.w = o.w * fminf(fmaxf(o.w + 3.0f, 0.0f), 6.0f) * (1.0f / 6.0f);
        __builtin_nontemporal_store(r, &op[i]);
    }
}

extern "C" void kernel_launch(void* const* d_in, const int* in_sizes, int n_in,
                              void* d_out, int out_size, void* d_ws, size_t ws_size,
                              hipStream_t stream) {
    const float* x     = (const float*)d_in[0];
    const float* bn1_g = (const float*)d_in[1];
    const float* bn1_b = (const float*)d_in[2];
    const float* bn1_m = (const float*)d_in[3];
    const float* bn1_v = (const float*)d_in[4];
    const float* bn2_g = (const float*)d_in[5];
    const float* bn2_b = (const float*)d_in[6];
    const float* bn2_m = (const float*)d_in[7];
    const float* bn2_v = (const float*)d_in[8];
    const float* ds_w  = (const float*)d_in[9];
    const float* ds_b  = (const float*)d_in[10];
    const float* us_w  = (const float*)d_in[11];
    const float* us_b  = (const float*)d_in[12];
    float* out = (float*)d_out;
    float* pool = (float*)d_ws;   // 2*N*112*C*4 = 1.75 MB

    pool_kernel<<<NN * CC, 256, 0, stream>>>(x, pool);
    att_kernel<<<dim3(NN * HH, 2), 256, 0, stream>>>(pool,
        bn1_g, bn1_b, bn1_m, bn1_v, bn2_g, bn2_b, bn2_m, bn2_v,
        ds_w, ds_b, us_w, us_b);
    apply_kernel<<<NN * CC, 256, 0, stream>>>(x, pool, out);
}